// Round 4
// baseline (341.701 us; speedup 1.0000x reference)
//
#include <hip/hip_runtime.h>

// SimpleEdgeModel round 10: 32x32x16 MFMA + in-register e2 handoff.
// R9 post-mortem: VGPR_Count=104 proves the compiler rematerialized the
// "stationary" W3 regs (const __restrict__ loads get re-executed) -> back to
// L1-bound + per-step barrier; and even a fixed R9 is ~61k DS-cy/CU (~25us).
// Root problem since R6: per (i, 32j) a wave moves 64KB weights + 16KB e2
// roundtrip through one pipe (L1 in R6, DS in R8 -> 82k DS-cy/CU vs 40k
// MFMA-cy/SIMD, matches 42.4us @ MfmaUtil 32%).
// Fix: (1) 32x32x16 MFMA (full-rate 2382 TF), wave owns 64 j -> weight
// bytes per FLOP halve; (2) the 32x32 C-layout row=(r&3)+8(r>>2)+4h maps
// onto the 32x32x16 B-frag k=8h+e with ONE lane<->lane+32 half-swap:
//   kt3-even frag: h=0 lanes [pkA@h0|pkA@h1], h=1 lanes [pkB@h0|pkB@h1],
//   pkA/pkB = f16-packed acc regs 0-3/4-7  (4 shfl_xor(32) + 4 selects).
// e2 never touches LDS; LDS = weights 64KB + biases 1.5KB only.
// Budget/CU: DS ~42k cy, MFMA ~34.6k cy/SIMD, VALU ~12k -> balanced,
// 2 waves/SIMD overlap.  shfl_xor chosen over v_permlane32_swap (operand
// direction unverified; swap is the follow-up if DS still limits).
//
// out[b,i,j] = Wo.relu(W3^T.relu(W2^T.relu(g_j+bc1-g_i)+bc2)+bc3)+bo
// g = nodeMLP(x)@Wc1.

typedef _Float16 half_t;
typedef __attribute__((ext_vector_type(2))) _Float16 f16x2;
typedef __attribute__((ext_vector_type(8))) _Float16 f16x8;
typedef __attribute__((ext_vector_type(4))) float f32x4;
typedef __attribute__((ext_vector_type(16))) float f32x16;

// ws layout:
//   gh  : 1024*128 f16 @ 0        = f16(g)
//   gbh : 1024*128 f16 @ 262144   = f16(g + bc1)
//   W2T : 16384 f16    @ 524288   (32x32x16 A-frags, idx f=nt32*8+kt)
//   W3T : 16384 f16    @ 557056   (same layout for Wc3)

// ---------------------------------------------------------------------------
// prep: blocks 0..255 node MLP (4 nodes/block); 256..271 weight frag pack.
// A-frag (32x32x16): lane L, elem e <- Wsrc[kt*16 + 8*(L>>5) + e][nt32*32 + (L&31)]
// ---------------------------------------------------------------------------
__global__ __launch_bounds__(256) void prep_kernel(
    const float* __restrict__ x, const float* __restrict__ Wa, const float* __restrict__ ba,
    const float* __restrict__ Wb, const float* __restrict__ bb, const float* __restrict__ Wc1,
    const float* __restrict__ bc1, const float* __restrict__ Wc2, const float* __restrict__ Wc3,
    half_t* __restrict__ gh, half_t* __restrict__ gbh,
    half_t* __restrict__ W2T, half_t* __restrict__ W3T)
{
  const int t = threadIdx.x;
  if (blockIdx.x >= 256) {
    const int bid = blockIdx.x - 256;            // 0..15: layer(1b) x fgroup(3b)
    const int layer = bid >> 3;
    const int f = (bid & 7) * 4 + (t >> 6);      // frag 0..31 = nt32*8 + kt
    const int L = t & 63;
    const int nt32 = f >> 3, kt = f & 7;
    const int row0 = kt * 16 + 8 * (L >> 5);
    const int col = nt32 * 32 + (L & 31);
    const float* src = layer ? Wc3 : Wc2;
    half_t* dst = layer ? W3T : W2T;
    f16x8 v;
    #pragma unroll
    for (int e = 0; e < 8; e++)
      v[e] = (half_t)src[(row0 + e) * 128 + col];
    *(f16x8*)(dst + f * 512 + L * 8) = v;
    return;
  }
  __shared__ float sx[64 * 6];
  __shared__ float sh1[128 * 6];
  __shared__ float sh2[128 * 6];
  const int n0 = blockIdx.x * 4;
  const int col = t & 127, hf = t >> 7;

  sx[(t & 63) * 6 + (t >> 6)] = x[(n0 + (t >> 6)) * 64 + (t & 63)];
  __syncthreads();

  float a0 = ba[col], a1 = a0;
  #pragma unroll
  for (int cc = 0; cc < 64; cc++) {
    const float wv = Wa[cc * 128 + col];
    const float2 xv = *(const float2*)(sx + cc * 6 + hf * 2);
    a0 = fmaf(xv.x, wv, a0); a1 = fmaf(xv.y, wv, a1);
  }
  *(float2*)(sh1 + col * 6 + hf * 2) = make_float2(fmaxf(a0, 0.f), fmaxf(a1, 0.f));
  __syncthreads();

  float b0 = bb[col], b1 = b0;
  #pragma unroll
  for (int k = 0; k < 128; k++) {
    const float wv = Wb[k * 128 + col];
    const float2 hv = *(const float2*)(sh1 + k * 6 + hf * 2);
    b0 = fmaf(hv.x, wv, b0); b1 = fmaf(hv.y, wv, b1);
  }
  *(float2*)(sh2 + col * 6 + hf * 2) = make_float2(fmaxf(b0, 0.f), fmaxf(b1, 0.f));
  __syncthreads();

  float c0 = 0.f, c1 = 0.f;
  #pragma unroll
  for (int k = 0; k < 128; k++) {
    const float wv = Wc1[k * 128 + col];
    const float2 hv = *(const float2*)(sh2 + k * 6 + hf * 2);
    c0 = fmaf(hv.x, wv, c0); c1 = fmaf(hv.y, wv, c1);
  }
  const float bv = bc1[col];
  const int r0 = n0 + hf * 2;
  gh [(r0 + 0) * 128 + col] = (half_t)c0;
  gh [(r0 + 1) * 128 + col] = (half_t)c1;
  gbh[(r0 + 0) * 128 + col] = (half_t)(c0 + bv);
  gbh[(r0 + 1) * 128 + col] = (half_t)(c1 + bv);
}

// ---------------------------------------------------------------------------
// edge kernel. 256 blocks x 512 threads = b(1b) x ichunk(7b, 4 i each).
// Wave w owns j-rows [w*64, +64) as 2 j-tiles of 32; block covers all 512 j.
// LDS: sW2/sW3 64KB (block-shared A-frags) + biases; e2 in registers.
// ---------------------------------------------------------------------------
static __device__ inline f16x8 relu_sub8(f16x8 a, f16x8 b) {
  f16x8 d = a - b;
  const f16x8 z = {};
  return __builtin_elementwise_max(d, z);
}

static __device__ inline unsigned pack2relu(float a, float b) {
  f16x2 hx;
  hx[0] = (half_t)fmaxf(a, 0.f);
  hx[1] = (half_t)fmaxf(b, 0.f);
  return __builtin_bit_cast(unsigned, hx);
}

__global__ __launch_bounds__(512, 2)
void edge_kernel(
    const half_t* __restrict__ gh, const half_t* __restrict__ gbh,
    const half_t* __restrict__ W2T, const half_t* __restrict__ W3T,
    const float* __restrict__ bc2, const float* __restrict__ bc3,
    const float* __restrict__ Wo, const float* __restrict__ bo,
    float* __restrict__ out)
{
  __shared__ __align__(16) half_t sW2[16384];    // 32 KB
  __shared__ __align__(16) half_t sW3[16384];    // 32 KB
  __shared__ __align__(16) float  sBf[384];      // bc2 | bc3 | Wo  (1.5 KB)

  const int t = threadIdx.x, lane = t & 63, w = t >> 6;
  const int h = lane >> 5, c32 = lane & 31;
  const int bid = blockIdx.x;
  const int b = bid >> 7, ic = bid & 127;
  const int i0 = ic * 4;
  const int j0 = w * 64;
  const bool hs = (h != 0);

  // ---- stage weights + biases into LDS (once per block) ----
  #pragma unroll
  for (int k = 0; k < 4; k++) {
    const int off = (k * 512 + t) * 8;
    *(f16x8*)(sW2 + off) = *(const f16x8*)(W2T + off);
    *(f16x8*)(sW3 + off) = *(const f16x8*)(W3T + off);
  }
  if (t < 384) sBf[t] = (t < 128) ? bc2[t] : ((t < 256) ? bc3[t - 128] : Wo[t - 256]);
  __syncthreads();

  const float bo0 = bo[0];
  const int rdoff = lane * 8;

  #pragma unroll 1
  for (int u = 0; u < 4; u++) {
    const int i = i0 + u;

    // ---- phase A: e1 B-frags (k = kt*16 + 8h + e), 64 VGPRs ----
    f16x8 e1[2][8];
    {
      f16x8 gi[8];
      #pragma unroll
      for (int kt = 0; kt < 8; kt++)
        gi[kt] = *(const f16x8*)(gh + (size_t)(b * 512 + i) * 128 + kt * 16 + 8 * h);
      #pragma unroll
      for (int jt = 0; jt < 2; jt++)
        #pragma unroll
        for (int kt = 0; kt < 8; kt++) {
          const f16x8 gj = *(const f16x8*)(gbh + (size_t)(b * 512 + j0 + jt * 32 + c32) * 128 + kt * 16 + 8 * h);
          e1[jt][kt] = relu_sub8(gj, gi[kt]);
        }
    }

    // ---- phase B: layer 2 (4 n-tiles of 32); e2 stays in registers ----
    f16x8 e2f[2][8];                             // [jt][kt3] B-frags, 64 VGPRs
    #pragma unroll
    for (int nt = 0; nt < 4; nt++) {
      f32x4 b2q[4];
      #pragma unroll
      for (int rq = 0; rq < 4; rq++)
        b2q[rq] = *(const f32x4*)(sBf + nt * 32 + rq * 8 + h * 4);
      f32x16 acc0, acc1;
      #pragma unroll
      for (int r = 0; r < 16; r++) acc0[r] = b2q[r >> 2][r & 3];
      acc1 = acc0;
      __builtin_amdgcn_s_setprio(1);
      #pragma unroll
      for (int kt = 0; kt < 8; kt++) {
        const f16x8 wf = *(const f16x8*)(sW2 + (nt * 8 + kt) * 512 + rdoff);
        acc0 = __builtin_amdgcn_mfma_f32_32x32x16_f16(wf, e1[0][kt], acc0, 0, 0, 0);
        acc1 = __builtin_amdgcn_mfma_f32_32x32x16_f16(wf, e1[1][kt], acc1, 0, 0, 0);
      }
      __builtin_amdgcn_s_setprio(0);
      // relu+pack acc -> B-frags for layer 3 (kt3 = 2nt, 2nt+1), half-swap
      #pragma unroll
      for (int jt = 0; jt < 2; jt++) {
        const f32x16 a = jt ? acc1 : acc0;
        {  // kt3 even: acc regs 0..7
          const unsigned u0 = pack2relu(a[0], a[1]),  u1 = pack2relu(a[2], a[3]);
          const unsigned u2 = pack2relu(a[4], a[5]),  u3 = pack2relu(a[6], a[7]);
          const unsigned s0 = __shfl_xor(u0, 32, 64), s1 = __shfl_xor(u1, 32, 64);
          const unsigned s2 = __shfl_xor(u2, 32, 64), s3 = __shfl_xor(u3, 32, 64);
          uint4 fu;
          fu.x = hs ? s2 : u0; fu.y = hs ? s3 : u1;
          fu.z = hs ? u2 : s0; fu.w = hs ? u3 : s1;
          e2f[jt][2 * nt] = __builtin_bit_cast(f16x8, fu);
        }
        {  // kt3 odd: acc regs 8..15
          const unsigned u0 = pack2relu(a[8],  a[9]),  u1 = pack2relu(a[10], a[11]);
          const unsigned u2 = pack2relu(a[12], a[13]), u3 = pack2relu(a[14], a[15]);
          const unsigned s0 = __shfl_xor(u0, 32, 64), s1 = __shfl_xor(u1, 32, 64);
          const unsigned s2 = __shfl_xor(u2, 32, 64), s3 = __shfl_xor(u3, 32, 64);
          uint4 fu;
          fu.x = hs ? s2 : u0; fu.y = hs ? s3 : u1;
          fu.z = hs ? u2 : s0; fu.w = hs ? u3 : s1;
          e2f[jt][2 * nt + 1] = __builtin_bit_cast(f16x8, fu);
        }
      }
    }

    // ---- phase C: layer 3 (4 m-tiles of 32), fused Wo reduction ----
    float p0 = 0.f, p1 = 0.f;
    #pragma unroll
    for (int mt = 0; mt < 4; mt++) {
      f32x4 b3q[4], woq[4];
      #pragma unroll
      for (int rq = 0; rq < 4; rq++) {
        b3q[rq] = *(const f32x4*)(sBf + 128 + mt * 32 + rq * 8 + h * 4);
        woq[rq] = *(const f32x4*)(sBf + 256 + mt * 32 + rq * 8 + h * 4);
      }
      f32x16 a0, a1;
      #pragma unroll
      for (int r = 0; r < 16; r++) a0[r] = b3q[r >> 2][r & 3];
      a1 = a0;
      __builtin_amdgcn_s_setprio(1);
      #pragma unroll
      for (int kt = 0; kt < 8; kt++) {
        const f16x8 wf = *(const f16x8*)(sW3 + (mt * 8 + kt) * 512 + rdoff);
        a0 = __builtin_amdgcn_mfma_f32_32x32x16_f16(wf, e2f[0][kt], a0, 0, 0, 0);
        a1 = __builtin_amdgcn_mfma_f32_32x32x16_f16(wf, e2f[1][kt], a1, 0, 0, 0);
      }
      __builtin_amdgcn_s_setprio(0);
      #pragma unroll
      for (int r = 0; r < 16; r++) {
        const float wv = woq[r >> 2][r & 3];
        p0 = fmaf(fmaxf(a0[r], 0.f), wv, p0);
        p1 = fmaf(fmaxf(a1[r], 0.f), wv, p1);
      }
    }

    // ---- epilogue: reduce across lane halves (m split over h), store ----
    p0 += __shfl_xor(p0, 32, 64);
    p1 += __shfl_xor(p1, 32, 64);
    if (h == 0) {
      const size_t base = ((size_t)(b * 512 + i)) * 512 + j0;
      out[base + c32]      = p0 + bo0;
      out[base + 32 + c32] = p1 + bo0;
    }
  }
}

// ---------------------------------------------------------------------------
extern "C" void kernel_launch(void* const* d_in, const int* in_sizes, int n_in,
                              void* d_out, int out_size, void* d_ws, size_t ws_size,
                              hipStream_t stream)
{
  const float* x   = (const float*)d_in[0];
  const float* Wa  = (const float*)d_in[1];
  const float* ba  = (const float*)d_in[2];
  const float* Wb  = (const float*)d_in[3];
  const float* bb  = (const float*)d_in[4];
  const float* Wc1 = (const float*)d_in[5];
  const float* bc1 = (const float*)d_in[6];
  const float* Wc2 = (const float*)d_in[7];
  const float* bc2 = (const float*)d_in[8];
  const float* Wc3 = (const float*)d_in[9];
  const float* bc3 = (const float*)d_in[10];
  const float* Wo  = (const float*)d_in[11];
  const float* bo  = (const float*)d_in[12];
  float* out = (float*)d_out;

  char* ws = (char*)d_ws;
  half_t* gh  = (half_t*)ws;                      // 256 KB
  half_t* gbh = (half_t*)(ws + 262144);           // 256 KB
  half_t* W2T = (half_t*)(ws + 524288);           // 32 KB
  half_t* W3T = (half_t*)(ws + 557056);           // 32 KB

  prep_kernel<<<272, 256, 0, stream>>>(x, Wa, ba, Wb, bb, Wc1, bc1, Wc2, Wc3,
                                       gh, gbh, W2T, W3T);
  edge_kernel<<<256, 512, 0, stream>>>(gh, gbh, W2T, W3T, bc2, bc3, Wo, bo, out);
}

// Round 5
// 151.992 us; speedup vs baseline: 2.2482x; 2.2482x over previous
//
#include <hip/hip_runtime.h>

// SimpleEdgeModel round 11: producer/consumer with weights-from-LDS, jt=4.
// R10 post-mortem: in-register e2 needed ~190 regs; backend pins 128 (prior
// session R4/R5 note) -> ~60 regs spilled, FETCH 437MB of scratch, 268us.
// HARD RULE: <=~116 live VGPRs.  DS audit: weight-frag reads dominate every
// design (64 reads x 12cy per (i,32j)); only fix within the reg wall is
// role-split so each wave holds ONE layer's state at jt=4:
//   waves 0-1: layer-2 producers, 64 j each, e1[4][4]=64 regs, W2 from LDS;
//   waves 2-3: layer-3 consumers, 64 j each, be[4][4]=64 regs, W3 from LDS.
// jt=4 -> each wf read feeds 4 MFMAs -> wf reads HALVE vs R8: DS ~39k cy/CU
// vs MFMA ~40k cy/CU -> balanced.  LDS = 32(W2)+32(W3)+64(sE dbuf)+1.5 =
// 132.6 KB, 1 block/CU, 17 rounds x 1 i, one barrier/round; producer writes
// slot r&1, consumer reads slot (r-1)&1 (never same slot between barriers).
// Unlike R9: no register-stationary weights (nothing to remat), balanced
// per-round work (~2.5k cy/side).  1 wave/SIMD is the accepted risk: per nt
// the MFMA cluster (~310 cy/SIMD) dwarfs its 4 ds_reads (~50 cy).
//
// out[b,i,j] = Wo.relu(W3^T.relu(W2^T.relu(g_j+bc1-g_i)+bc2)+bc3)+bo
// g = nodeMLP(x)@Wc1.

typedef _Float16 half_t;
typedef __attribute__((ext_vector_type(2))) _Float16 f16x2;
typedef __attribute__((ext_vector_type(8))) _Float16 f16x8;
typedef __attribute__((ext_vector_type(4))) float f32x4;

// ws layout:
//   gh  : 1024*128 f16 @ 0        = f16(g)
//   gbh : 1024*128 f16 @ 262144   = f16(g + bc1)
//   W2T : 16384 f16    @ 524288   (frag-packed Wc2, (nt*4+ks) order)
//   W3T : 16384 f16    @ 557056

// ---------------------------------------------------------------------------
// prep: blocks 0..255 node MLP (4 nodes/block); 256..271 weight frag pack.
// Frag (nt,ks), lane L=q*16+c, elem e  <-  Wsrc[32ks+8q+e][16nt+c].
// ---------------------------------------------------------------------------
__global__ __launch_bounds__(256) void prep_kernel(
    const float* __restrict__ x, const float* __restrict__ Wa, const float* __restrict__ ba,
    const float* __restrict__ Wb, const float* __restrict__ bb, const float* __restrict__ Wc1,
    const float* __restrict__ bc1, const float* __restrict__ Wc2, const float* __restrict__ Wc3,
    half_t* __restrict__ gh, half_t* __restrict__ gbh,
    half_t* __restrict__ W2T, half_t* __restrict__ W3T)
{
  const int t = threadIdx.x;
  if (blockIdx.x >= 256) {
    const int bid = blockIdx.x - 256;            // layer(1b) x ntile(3b)
    const int layer = bid >> 3, nt = bid & 7;
    const int ks = t >> 6, L = t & 63, q = L >> 4, cc = L & 15;
    const float* src = layer ? Wc3 : Wc2;
    half_t* dst = layer ? W3T : W2T;
    f16x8 v;
    #pragma unroll
    for (int e = 0; e < 8; e++)
      v[e] = (half_t)src[(32 * ks + 8 * q + e) * 128 + 16 * nt + cc];
    *(f16x8*)(dst + (nt * 4 + ks) * 512 + L * 8) = v;   // ks-frags contiguous per nt
    return;
  }
  __shared__ float sx[64 * 6];
  __shared__ float sh1[128 * 6];
  __shared__ float sh2[128 * 6];
  const int n0 = blockIdx.x * 4;
  const int col = t & 127, hf = t >> 7;

  sx[(t & 63) * 6 + (t >> 6)] = x[(n0 + (t >> 6)) * 64 + (t & 63)];
  __syncthreads();

  float a0 = ba[col], a1 = a0;
  #pragma unroll
  for (int cc = 0; cc < 64; cc++) {
    const float wv = Wa[cc * 128 + col];
    const float2 xv = *(const float2*)(sx + cc * 6 + hf * 2);
    a0 = fmaf(xv.x, wv, a0); a1 = fmaf(xv.y, wv, a1);
  }
  *(float2*)(sh1 + col * 6 + hf * 2) = make_float2(fmaxf(a0, 0.f), fmaxf(a1, 0.f));
  __syncthreads();

  float b0 = bb[col], b1 = b0;
  #pragma unroll
  for (int k = 0; k < 128; k++) {
    const float wv = Wb[k * 128 + col];
    const float2 hv = *(const float2*)(sh1 + k * 6 + hf * 2);
    b0 = fmaf(hv.x, wv, b0); b1 = fmaf(hv.y, wv, b1);
  }
  *(float2*)(sh2 + col * 6 + hf * 2) = make_float2(fmaxf(b0, 0.f), fmaxf(b1, 0.f));
  __syncthreads();

  float c0 = 0.f, c1 = 0.f;
  #pragma unroll
  for (int k = 0; k < 128; k++) {
    const float wv = Wc1[k * 128 + col];
    const float2 hv = *(const float2*)(sh2 + k * 6 + hf * 2);
    c0 = fmaf(hv.x, wv, c0); c1 = fmaf(hv.y, wv, c1);
  }
  const float bv = bc1[col];
  const int r0 = n0 + hf * 2;
  gh [(r0 + 0) * 128 + col] = (half_t)c0;
  gh [(r0 + 1) * 128 + col] = (half_t)c1;
  gbh[(r0 + 0) * 128 + col] = (half_t)(c0 + bv);
  gbh[(r0 + 1) * 128 + col] = (half_t)(c1 + bv);
}

// ---------------------------------------------------------------------------
// edge kernel. 256 blocks x 256 threads = b(1b) x jq(2b) x ic(5b, 16 i each).
// Waves 0-1: producers (layer 2), wave pw owns j [jq*128+pw*64, +64).
// Waves 2-3: consumers (layer 3), same j-range as producer pw=w-2.
// 17 rounds, 1 i/round; sE double-buffered per producer; 1 barrier/round.
// ---------------------------------------------------------------------------
static __device__ inline f16x8 relu_sub8(f16x8 a, f16x8 b) {
  f16x8 d = a - b;
  const f16x8 z = {};
  return __builtin_elementwise_max(d, z);
}

__global__ __launch_bounds__(256)
void edge_kernel(
    const half_t* __restrict__ gh, const half_t* __restrict__ gbh,
    const half_t* __restrict__ W2T, const half_t* __restrict__ W3T,
    const float* __restrict__ bc2, const float* __restrict__ bc3,
    const float* __restrict__ Wo, const float* __restrict__ bo,
    float* __restrict__ out)
{
  __shared__ __align__(16) half_t sW2[16384];    // 32 KB
  __shared__ __align__(16) half_t sW3[16384];    // 32 KB
  __shared__ __align__(16) float  sBf[384];      // bc2 | bc3 | Wo  (1.5 KB)
  __shared__ __align__(16) half_t sE[32768];     // 64 KB: [pw][slot][8192]

  const int t = threadIdx.x, lane = t & 63, w = t >> 6;
  const int c = lane & 15, q = lane >> 4;
  const int bid = blockIdx.x;
  const int b = bid >> 7, jq = (bid >> 5) & 3, ic = bid & 31;
  const int i0 = ic * 16;
  const bool producer = (w < 2);
  const int pw = producer ? w : (w - 2);
  const int j0 = jq * 128 + pw * 64;

  // ---- stage weights + biases into LDS (once per block) ----
  #pragma unroll
  for (int k = 0; k < 8; k++) {
    const int off = (k * 256 + t) * 8;
    *(f16x8*)(sW2 + off) = *(const f16x8*)(W2T + off);
    *(f16x8*)(sW3 + off) = *(const f16x8*)(W3T + off);
  }
  for (int s = t; s < 384; s += 256)
    sBf[s] = (s < 128) ? bc2[s] : ((s < 256) ? bc3[s - 128] : Wo[s - 256]);
  __syncthreads();

  const float bo0 = bo[0];
  // LDS pack address (halfs): ((q>>1)*16+c)*8 + (q&1)*4; +256 halfs when nt odd
  const int packoff = ((q >> 1) * 16 + c) * 8 + (q & 1) * 4;
  const int rdoff = lane * 8;

  #pragma unroll 1
  for (int r = 0; r < 17; ++r) {
    if (producer) {
      if (r < 16) {
        const int i = i0 + r;
        // ---- phase A: e1[ks][jt] (64 VGPRs) ----
        f16x8 e1[4][4];
        {
          f16x8 gih[4];
          #pragma unroll
          for (int ks = 0; ks < 4; ks++)
            gih[ks] = *(const f16x8*)(gh + (size_t)(b * 512 + i) * 128 + ks * 32 + q * 8);
          #pragma unroll
          for (int ks = 0; ks < 4; ks++)
            #pragma unroll
            for (int jt = 0; jt < 4; jt++) {
              const f16x8 gj = *(const f16x8*)(gbh + (size_t)(b * 512 + j0 + jt * 16 + c) * 128 + ks * 32 + q * 8);
              e1[ks][jt] = relu_sub8(gj, gih[ks]);
            }
        }
        // ---- phase B: layer 2, W2 from LDS; pack e2 -> slot r&1 ----
        half_t* sEw = sE + (pw * 2 + (r & 1)) * 8192;
        #pragma unroll 1
        for (int nt = 0; nt < 8; nt++) {
          f16x8 wf[4];
          #pragma unroll
          for (int ks = 0; ks < 4; ks++)
            wf[ks] = *(const f16x8*)(sW2 + (nt * 4 + ks) * 512 + rdoff);
          const f32x4 b2 = *(const f32x4*)(sBf + nt * 16 + q * 4);
          f32x4 acc[4] = {b2, b2, b2, b2};
          __builtin_amdgcn_s_setprio(1);
          #pragma unroll
          for (int ks = 0; ks < 4; ks++)
            #pragma unroll
            for (int jt = 0; jt < 4; jt++)
              acc[jt] = __builtin_amdgcn_mfma_f32_16x16x32_f16(wf[ks], e1[ks][jt], acc[jt], 0, 0, 0);
          __builtin_amdgcn_s_setprio(0);
          const int po = ((nt >> 1) * 512) + packoff + (nt & 1) * 256;   // ks3 slot base
          #pragma unroll
          for (int jt = 0; jt < 4; jt++) {
            const f32x4 v = acc[jt];
            f16x2 h01, h23;
            h01[0] = (half_t)fmaxf(v[0], 0.f); h01[1] = (half_t)fmaxf(v[1], 0.f);
            h23[0] = (half_t)fmaxf(v[2], 0.f); h23[1] = (half_t)fmaxf(v[3], 0.f);
            uint2 uv;
            uv.x = __builtin_bit_cast(unsigned int, h01);
            uv.y = __builtin_bit_cast(unsigned int, h23);
            *(uint2*)(sEw + jt * 2048 + po) = uv;    // (jt*4+ks3)*512 = jt*2048+ks3*512
          }
        }
      }
    } else {
      if (r >= 1) {
        const int i = i0 + r - 1;
        // ---- phase C: layer 3; be from slot (r-1)&1, W3 from LDS ----
        const half_t* sEc = sE + (pw * 2 + ((r - 1) & 1)) * 8192;
        f16x8 be[4][4];
        #pragma unroll
        for (int ks3 = 0; ks3 < 4; ks3++)
          #pragma unroll
          for (int jt = 0; jt < 4; jt++)
            be[ks3][jt] = *(const f16x8*)(sEc + (jt * 4 + ks3) * 512 + rdoff);

        float p[4] = {0.f, 0.f, 0.f, 0.f};
        #pragma unroll 1
        for (int mt = 0; mt < 8; mt++) {
          f16x8 wf[4];
          #pragma unroll
          for (int ks3 = 0; ks3 < 4; ks3++)
            wf[ks3] = *(const f16x8*)(sW3 + (mt * 4 + ks3) * 512 + rdoff);
          const f32x4 b3 = *(const f32x4*)(sBf + 128 + mt * 16 + q * 4);
          f32x4 acc[4] = {b3, b3, b3, b3};
          __builtin_amdgcn_s_setprio(1);
          #pragma unroll
          for (int ks3 = 0; ks3 < 4; ks3++)
            #pragma unroll
            for (int jt = 0; jt < 4; jt++)
              acc[jt] = __builtin_amdgcn_mfma_f32_16x16x32_f16(wf[ks3], be[ks3][jt], acc[jt], 0, 0, 0);
          __builtin_amdgcn_s_setprio(0);
          const f32x4 wo = *(const f32x4*)(sBf + 256 + mt * 16 + q * 4);
          #pragma unroll
          for (int jt = 0; jt < 4; jt++)
            #pragma unroll
            for (int rr = 0; rr < 4; rr++)
              p[jt] = fmaf(fmaxf(acc[jt][rr], 0.f), wo[rr], p[jt]);
        }
        // ---- epilogue: reduce over q (rows n3 split across q), store ----
        #pragma unroll
        for (int jt = 0; jt < 4; jt++) {
          p[jt] += __shfl_xor(p[jt], 16, 64);
          p[jt] += __shfl_xor(p[jt], 32, 64);
        }
        if (q == 0) {
          const size_t base = ((size_t)(b * 512 + i)) * 512 + j0;
          #pragma unroll
          for (int jt = 0; jt < 4; jt++)
            out[base + jt * 16 + c] = p[jt] + bo0;
        }
      }
    }
    __syncthreads();
  }
}

// ---------------------------------------------------------------------------
extern "C" void kernel_launch(void* const* d_in, const int* in_sizes, int n_in,
                              void* d_out, int out_size, void* d_ws, size_t ws_size,
                              hipStream_t stream)
{
  const float* x   = (const float*)d_in[0];
  const float* Wa  = (const float*)d_in[1];
  const float* ba  = (const float*)d_in[2];
  const float* Wb  = (const float*)d_in[3];
  const float* bb  = (const float*)d_in[4];
  const float* Wc1 = (const float*)d_in[5];
  const float* bc1 = (const float*)d_in[6];
  const float* Wc2 = (const float*)d_in[7];
  const float* bc2 = (const float*)d_in[8];
  const float* Wc3 = (const float*)d_in[9];
  const float* bc3 = (const float*)d_in[10];
  const float* Wo  = (const float*)d_in[11];
  const float* bo  = (const float*)d_in[12];
  float* out = (float*)d_out;

  char* ws = (char*)d_ws;
  half_t* gh  = (half_t*)ws;                      // 256 KB
  half_t* gbh = (half_t*)(ws + 262144);           // 256 KB
  half_t* W2T = (half_t*)(ws + 524288);           // 32 KB
  half_t* W3T = (half_t*)(ws + 557056);           // 32 KB

  prep_kernel<<<272, 256, 0, stream>>>(x, Wa, ba, Wb, bb, Wc1, bc1, Wc2, Wc3,
                                       gh, gbh, W2T, W3T);
  edge_kernel<<<256, 256, 0, stream>>>(gh, gbh, W2T, W3T, bc2, bc3, Wo, bo, out);
}

// Round 6
// 128.353 us; speedup vs baseline: 2.6622x; 1.1842x over previous
//
#include <hip/hip_runtime.h>

// SimpleEdgeModel round 12: P/C specialization at jt=4, 8 waves, 1 P + 1 C
// per SIMD, single-buffered handoff.
// R11 post-mortem: 4 waves = 1/SIMD and (under wave%4 SIMD mapping) P-only /
// C-only SIMDs -> all latency exposed, 72us, MfmaUtil 18%.  Also jt=2 P/C
// gives ZERO weight-read amortization (P+C = 64 wf reads per 32 j = R8).
// Invariants: VGPR<=~116 live (R10: 128-pin + spills); >=2 waves/SIMD (R11);
// weight stream/CU: 4MB @jt=2 (49k DS-cy = R8's 42us wall) vs 2MB @jt=4.
// Fix: jt=4 needs 64(state)+16(wf)+16(acc) regs for ONE layer -> role split:
//   waves 0-3 producers (layer2, e1[4][4], W2 from LDS),
//   waves 4-7 consumers (layer3, be[4][4], W3 from LDS);
//   w and w+4 share a SIMD under wave%4 -> each SIMD gets 1P+1C overlap.
// Handoff: single 16KB buffer per pair + 2 barriers/round: C pre-reads be
// into 64 regs BEFORE bar1; P overwrites the slot after bar1 while C does
// layer3 from regs.  LDS = 64(W2+W3) + 64(4x16KB) + 1.5 = 129.6KB, 1 blk/CU.
// Per round/SIMD: MFMA (128+128)x19.4 ~ 4966 cy >> DS ~4k cy/CU -> MFMA-
// bound.  8 i-rounds + fill/drain ~ 19-21us predicted (R8 edge: 42.4).
//
// out[b,i,j] = Wo.relu(W3^T.relu(W2^T.relu(g_j+bc1-g_i)+bc2)+bc3)+bo
// g = nodeMLP(x)@Wc1.

typedef _Float16 half_t;
typedef __attribute__((ext_vector_type(2))) _Float16 f16x2;
typedef __attribute__((ext_vector_type(8))) _Float16 f16x8;
typedef __attribute__((ext_vector_type(4))) float f32x4;

// ws layout:
//   gh  : 1024*128 f16 @ 0        = f16(g)
//   gbh : 1024*128 f16 @ 262144   = f16(g + bc1)
//   W2T : 16384 f16    @ 524288   (frag-packed Wc2, (nt*4+ks) order)
//   W3T : 16384 f16    @ 557056

// ---------------------------------------------------------------------------
// prep: blocks 0..255 node MLP (4 nodes/block); 256..271 weight frag pack.
// Frag (nt,ks), lane L=q*16+c, elem e  <-  Wsrc[32ks+8q+e][16nt+c].
// ---------------------------------------------------------------------------
__global__ __launch_bounds__(256) void prep_kernel(
    const float* __restrict__ x, const float* __restrict__ Wa, const float* __restrict__ ba,
    const float* __restrict__ Wb, const float* __restrict__ bb, const float* __restrict__ Wc1,
    const float* __restrict__ bc1, const float* __restrict__ Wc2, const float* __restrict__ Wc3,
    half_t* __restrict__ gh, half_t* __restrict__ gbh,
    half_t* __restrict__ W2T, half_t* __restrict__ W3T)
{
  const int t = threadIdx.x;
  if (blockIdx.x >= 256) {
    const int bid = blockIdx.x - 256;            // layer(1b) x ntile(3b)
    const int layer = bid >> 3, nt = bid & 7;
    const int ks = t >> 6, L = t & 63, q = L >> 4, cc = L & 15;
    const float* src = layer ? Wc3 : Wc2;
    half_t* dst = layer ? W3T : W2T;
    f16x8 v;
    #pragma unroll
    for (int e = 0; e < 8; e++)
      v[e] = (half_t)src[(32 * ks + 8 * q + e) * 128 + 16 * nt + cc];
    *(f16x8*)(dst + (nt * 4 + ks) * 512 + L * 8) = v;   // ks-frags contiguous per nt
    return;
  }
  __shared__ float sx[64 * 6];
  __shared__ float sh1[128 * 6];
  __shared__ float sh2[128 * 6];
  const int n0 = blockIdx.x * 4;
  const int col = t & 127, hf = t >> 7;

  sx[(t & 63) * 6 + (t >> 6)] = x[(n0 + (t >> 6)) * 64 + (t & 63)];
  __syncthreads();

  float a0 = ba[col], a1 = a0;
  #pragma unroll
  for (int cc = 0; cc < 64; cc++) {
    const float wv = Wa[cc * 128 + col];
    const float2 xv = *(const float2*)(sx + cc * 6 + hf * 2);
    a0 = fmaf(xv.x, wv, a0); a1 = fmaf(xv.y, wv, a1);
  }
  *(float2*)(sh1 + col * 6 + hf * 2) = make_float2(fmaxf(a0, 0.f), fmaxf(a1, 0.f));
  __syncthreads();

  float b0 = bb[col], b1 = b0;
  #pragma unroll
  for (int k = 0; k < 128; k++) {
    const float wv = Wb[k * 128 + col];
    const float2 hv = *(const float2*)(sh1 + k * 6 + hf * 2);
    b0 = fmaf(hv.x, wv, b0); b1 = fmaf(hv.y, wv, b1);
  }
  *(float2*)(sh2 + col * 6 + hf * 2) = make_float2(fmaxf(b0, 0.f), fmaxf(b1, 0.f));
  __syncthreads();

  float c0 = 0.f, c1 = 0.f;
  #pragma unroll
  for (int k = 0; k < 128; k++) {
    const float wv = Wc1[k * 128 + col];
    const float2 hv = *(const float2*)(sh2 + k * 6 + hf * 2);
    c0 = fmaf(hv.x, wv, c0); c1 = fmaf(hv.y, wv, c1);
  }
  const float bv = bc1[col];
  const int r0 = n0 + hf * 2;
  gh [(r0 + 0) * 128 + col] = (half_t)c0;
  gh [(r0 + 1) * 128 + col] = (half_t)c1;
  gbh[(r0 + 0) * 128 + col] = (half_t)(c0 + bv);
  gbh[(r0 + 1) * 128 + col] = (half_t)(c1 + bv);
}

// ---------------------------------------------------------------------------
// edge kernel. 256 blocks x 512 threads = b(1b) x jhalf(1b) x ig(6b, 8 i).
// Waves 0-3: producers (layer 2, 64 j each); waves 4-7: consumers (layer 3,
// same 64 j as pair pw=w-4).  Under wave%4 SIMD mapping each SIMD hosts
// 1 P + 1 C.  Single 16KB handoff buffer per pair, 2 barriers/round:
//   [C: be<-LDS(prev i)] bar1 [P: layer2(i)->LDS | C: layer3 from regs] bar2
// ---------------------------------------------------------------------------
static __device__ inline f16x8 relu_sub8(f16x8 a, f16x8 b) {
  f16x8 d = a - b;
  const f16x8 z = {};
  return __builtin_elementwise_max(d, z);
}

__global__ __launch_bounds__(512)
void edge_kernel(
    const half_t* __restrict__ gh, const half_t* __restrict__ gbh,
    const half_t* __restrict__ W2T, const half_t* __restrict__ W3T,
    const float* __restrict__ bc2, const float* __restrict__ bc3,
    const float* __restrict__ Wo, const float* __restrict__ bo,
    float* __restrict__ out)
{
  __shared__ __align__(16) half_t sW2[16384];    // 32 KB
  __shared__ __align__(16) half_t sW3[16384];    // 32 KB
  __shared__ __align__(16) float  sBf[384];      // bc2 | bc3 | Wo  (1.5 KB)
  __shared__ __align__(16) half_t sE[32768];     // 64 KB: 4 pairs x 8192 halves

  const int t = threadIdx.x, lane = t & 63, w = t >> 6;
  const int c = lane & 15, q = lane >> 4;
  const int bid = blockIdx.x;
  const int b = bid >> 7, jh = (bid >> 6) & 1, ig = bid & 63;
  const int i0 = ig * 8;
  const bool producer = (w < 4);
  const int pw = w & 3;
  const int j0 = jh * 256 + pw * 64;

  // ---- stage weights + biases into LDS (once per block) ----
  #pragma unroll
  for (int k = 0; k < 4; k++) {
    const int off = (k * 512 + t) * 8;
    *(f16x8*)(sW2 + off) = *(const f16x8*)(W2T + off);
    *(f16x8*)(sW3 + off) = *(const f16x8*)(W3T + off);
  }
  if (t < 384) sBf[t] = (t < 128) ? bc2[t] : ((t < 256) ? bc3[t - 128] : Wo[t - 256]);
  __syncthreads();

  const float bo0 = bo[0];
  // LDS pack address (halfs): ((q>>1)*16+c)*8 + (q&1)*4; +256 halfs when nt odd
  const int packoff = ((q >> 1) * 16 + c) * 8 + (q & 1) * 4;
  const int rdoff = lane * 8;
  half_t* sEw = sE + pw * 8192;                  // pair's 16 KB slot

  #pragma unroll 1
  for (int r = 0; r < 9; ++r) {
    // ---- pre-bar1: consumer pulls be (written by its P in round r-1) ----
    f16x8 be[4][4];
    if (!producer && r >= 1) {
      #pragma unroll
      for (int ks3 = 0; ks3 < 4; ks3++)
        #pragma unroll
        for (int jt = 0; jt < 4; jt++)
          be[ks3][jt] = *(const f16x8*)(sEw + (jt * 4 + ks3) * 512 + rdoff);
    }
    __syncthreads();                             // bar1: be safe, slot free

    if (producer) {
      if (r < 8) {
        const int i = i0 + r;
        // ---- phase A: e1[ks][jt] (64 VGPRs) ----
        f16x8 e1[4][4];
        {
          f16x8 gih[4];
          #pragma unroll
          for (int ks = 0; ks < 4; ks++)
            gih[ks] = *(const f16x8*)(gh + (size_t)(b * 512 + i) * 128 + ks * 32 + q * 8);
          #pragma unroll
          for (int ks = 0; ks < 4; ks++)
            #pragma unroll
            for (int jt = 0; jt < 4; jt++) {
              const f16x8 gj = *(const f16x8*)(gbh + (size_t)(b * 512 + j0 + jt * 16 + c) * 128 + ks * 32 + q * 8);
              e1[ks][jt] = relu_sub8(gj, gih[ks]);
            }
        }
        // ---- phase B: layer 2, W2 from LDS; pack e2 -> pair slot ----
        #pragma unroll 1
        for (int nt = 0; nt < 8; nt++) {
          f16x8 wf[4];
          #pragma unroll
          for (int ks = 0; ks < 4; ks++)
            wf[ks] = *(const f16x8*)(sW2 + (nt * 4 + ks) * 512 + rdoff);
          const f32x4 b2 = *(const f32x4*)(sBf + nt * 16 + q * 4);
          f32x4 acc[4] = {b2, b2, b2, b2};
          __builtin_amdgcn_s_setprio(1);
          #pragma unroll
          for (int ks = 0; ks < 4; ks++)
            #pragma unroll
            for (int jt = 0; jt < 4; jt++)
              acc[jt] = __builtin_amdgcn_mfma_f32_16x16x32_f16(wf[ks], e1[ks][jt], acc[jt], 0, 0, 0);
          __builtin_amdgcn_s_setprio(0);
          const int po = ((nt >> 1) * 512) + packoff + (nt & 1) * 256;   // ks3 slot base
          #pragma unroll
          for (int jt = 0; jt < 4; jt++) {
            const f32x4 v = acc[jt];
            f16x2 h01, h23;
            h01[0] = (half_t)fmaxf(v[0], 0.f); h01[1] = (half_t)fmaxf(v[1], 0.f);
            h23[0] = (half_t)fmaxf(v[2], 0.f); h23[1] = (half_t)fmaxf(v[3], 0.f);
            uint2 uv;
            uv.x = __builtin_bit_cast(unsigned int, h01);
            uv.y = __builtin_bit_cast(unsigned int, h23);
            *(uint2*)(sEw + jt * 2048 + po) = uv;    // (jt*4+ks3)*512 = jt*2048+ks3*512
          }
        }
      }
    } else {
      if (r >= 1) {
        const int i = i0 + r - 1;
        // ---- phase C: layer 3 from be regs + sW3; fused Wo fold ----
        float p[4] = {0.f, 0.f, 0.f, 0.f};
        #pragma unroll 1
        for (int mt = 0; mt < 8; mt++) {
          f16x8 wf[4];
          #pragma unroll
          for (int ks3 = 0; ks3 < 4; ks3++)
            wf[ks3] = *(const f16x8*)(sW3 + (mt * 4 + ks3) * 512 + rdoff);
          const f32x4 b3 = *(const f32x4*)(sBf + 128 + mt * 16 + q * 4);
          f32x4 acc[4] = {b3, b3, b3, b3};
          __builtin_amdgcn_s_setprio(1);
          #pragma unroll
          for (int ks3 = 0; ks3 < 4; ks3++)
            #pragma unroll
            for (int jt = 0; jt < 4; jt++)
              acc[jt] = __builtin_amdgcn_mfma_f32_16x16x32_f16(wf[ks3], be[ks3][jt], acc[jt], 0, 0, 0);
          __builtin_amdgcn_s_setprio(0);
          const f32x4 wo = *(const f32x4*)(sBf + 256 + mt * 16 + q * 4);
          #pragma unroll
          for (int jt = 0; jt < 4; jt++)
            #pragma unroll
            for (int rr = 0; rr < 4; rr++)
              p[jt] = fmaf(fmaxf(acc[jt][rr], 0.f), wo[rr], p[jt]);
        }
        // ---- epilogue: reduce over q (rows split across q), store ----
        #pragma unroll
        for (int jt = 0; jt < 4; jt++) {
          p[jt] += __shfl_xor(p[jt], 16, 64);
          p[jt] += __shfl_xor(p[jt], 32, 64);
        }
        if (q == 0) {
          const size_t base = ((size_t)(b * 512 + i)) * 512 + j0;
          #pragma unroll
          for (int jt = 0; jt < 4; jt++)
            out[base + jt * 16 + c] = p[jt] + bo0;
        }
      }
    }
    __syncthreads();                             // bar2: slot filled for next round
  }
}

// ---------------------------------------------------------------------------
extern "C" void kernel_launch(void* const* d_in, const int* in_sizes, int n_in,
                              void* d_out, int out_size, void* d_ws, size_t ws_size,
                              hipStream_t stream)
{
  const float* x   = (const float*)d_in[0];
  const float* Wa  = (const float*)d_in[1];
  const float* ba  = (const float*)d_in[2];
  const float* Wb  = (const float*)d_in[3];
  const float* bb  = (const float*)d_in[4];
  const float* Wc1 = (const float*)d_in[5];
  const float* bc1 = (const float*)d_in[6];
  const float* Wc2 = (const float*)d_in[7];
  const float* bc2 = (const float*)d_in[8];
  const float* Wc3 = (const float*)d_in[9];
  const float* bc3 = (const float*)d_in[10];
  const float* Wo  = (const float*)d_in[11];
  const float* bo  = (const float*)d_in[12];
  float* out = (float*)d_out;

  char* ws = (char*)d_ws;
  half_t* gh  = (half_t*)ws;                      // 256 KB
  half_t* gbh = (half_t*)(ws + 262144);           // 256 KB
  half_t* W2T = (half_t*)(ws + 524288);           // 32 KB
  half_t* W3T = (half_t*)(ws + 557056);           // 32 KB

  prep_kernel<<<272, 256, 0, stream>>>(x, Wa, ba, Wb, bb, Wc1, bc1, Wc2, Wc3,
                                       gh, gbh, W2T, W3T);
  edge_kernel<<<256, 512, 0, stream>>>(gh, gbh, W2T, W3T, bc2, bc3, Wo, bo, out);
}

// Round 7
// 125.516 us; speedup vs baseline: 2.7224x; 1.0226x over previous
//
#include <hip/hip_runtime.h>

// SimpleEdgeModel round 13: R8 structure + software-pipelined weight frags.
// R12 post-mortem: jt=4 P/C halved the DS floor (39k cy/CU, no spills) but
// barrier lockstep at 2 waves/SIMD gave 3.0x floor (49.5us) vs R8's
// barrier-free 1.65x (42.4us).  Lesson: barrier-free self-scheduling wins;
// the residual in R8 is per-iteration latency: each unroll-1 nt-iter
// serializes {4 wf ds_reads -> lgkmcnt ~150cy -> 16 MFMA -> pack} = ~2.4k
// exposed cy per wave-u, plus ~300cy L2 wait on gih per u.
// Fix (no structural change):
//   1) wf a/b double-buffer: prefetch wf(nt+1) before computing nt, in both
//      phase B and C -> ds latency hides under the ~450cy MFMA cluster.
//   2) reload gih for u+1 right after e1 is built (gih dead there) -> L2
//      latency hides under phases B+C, zero extra regs.
// Live-reg audit: B ~110-115, C ~105 < 128 pin -> no spills expected
// (FETCH_SIZE flat is the check; R10 showed the balloon signature).
//
// out[b,i,j] = Wo.relu(W3^T.relu(W2^T.relu(g_j+bc1-g_i)+bc2)+bc3)+bo
// g = nodeMLP(x)@Wc1.  Per wave: 32 j-rows x 4 i-units; no barriers in loop.

typedef _Float16 half_t;
typedef __attribute__((ext_vector_type(2))) _Float16 f16x2;
typedef __attribute__((ext_vector_type(8))) _Float16 f16x8;
typedef __attribute__((ext_vector_type(4))) float f32x4;

// ws layout:
//   gh  : 1024*128 f16 @ 0        = f16(g)
//   gbh : 1024*128 f16 @ 262144   = f16(g + bc1)
//   W2T : 16384 f16    @ 524288   (frag-packed Wc2, (nt*4+ks) order)
//   W3T : 16384 f16    @ 557056

// ---------------------------------------------------------------------------
// prep: blocks 0..255 node MLP (4 nodes/block); 256..271 weight frag pack.
// Frag (nt,ks), lane L=q*16+c, elem e  <-  Wsrc[32ks+8q+e][16nt+c].
// ---------------------------------------------------------------------------
__global__ __launch_bounds__(256) void prep_kernel(
    const float* __restrict__ x, const float* __restrict__ Wa, const float* __restrict__ ba,
    const float* __restrict__ Wb, const float* __restrict__ bb, const float* __restrict__ Wc1,
    const float* __restrict__ bc1, const float* __restrict__ Wc2, const float* __restrict__ Wc3,
    half_t* __restrict__ gh, half_t* __restrict__ gbh,
    half_t* __restrict__ W2T, half_t* __restrict__ W3T)
{
  const int t = threadIdx.x;
  if (blockIdx.x >= 256) {
    const int bid = blockIdx.x - 256;            // layer(1b) x ntile(3b)
    const int layer = bid >> 3, nt = bid & 7;
    const int ks = t >> 6, L = t & 63, q = L >> 4, cc = L & 15;
    const float* src = layer ? Wc3 : Wc2;
    half_t* dst = layer ? W3T : W2T;
    f16x8 v;
    #pragma unroll
    for (int e = 0; e < 8; e++)
      v[e] = (half_t)src[(32 * ks + 8 * q + e) * 128 + 16 * nt + cc];
    *(f16x8*)(dst + (nt * 4 + ks) * 512 + L * 8) = v;   // ks-frags contiguous per nt
    return;
  }
  __shared__ float sx[64 * 6];
  __shared__ float sh1[128 * 6];
  __shared__ float sh2[128 * 6];
  const int n0 = blockIdx.x * 4;
  const int col = t & 127, hf = t >> 7;

  sx[(t & 63) * 6 + (t >> 6)] = x[(n0 + (t >> 6)) * 64 + (t & 63)];
  __syncthreads();

  float a0 = ba[col], a1 = a0;
  #pragma unroll
  for (int cc = 0; cc < 64; cc++) {
    const float wv = Wa[cc * 128 + col];
    const float2 xv = *(const float2*)(sx + cc * 6 + hf * 2);
    a0 = fmaf(xv.x, wv, a0); a1 = fmaf(xv.y, wv, a1);
  }
  *(float2*)(sh1 + col * 6 + hf * 2) = make_float2(fmaxf(a0, 0.f), fmaxf(a1, 0.f));
  __syncthreads();

  float b0 = bb[col], b1 = b0;
  #pragma unroll
  for (int k = 0; k < 128; k++) {
    const float wv = Wb[k * 128 + col];
    const float2 hv = *(const float2*)(sh1 + k * 6 + hf * 2);
    b0 = fmaf(hv.x, wv, b0); b1 = fmaf(hv.y, wv, b1);
  }
  *(float2*)(sh2 + col * 6 + hf * 2) = make_float2(fmaxf(b0, 0.f), fmaxf(b1, 0.f));
  __syncthreads();

  float c0 = 0.f, c1 = 0.f;
  #pragma unroll
  for (int k = 0; k < 128; k++) {
    const float wv = Wc1[k * 128 + col];
    const float2 hv = *(const float2*)(sh2 + k * 6 + hf * 2);
    c0 = fmaf(hv.x, wv, c0); c1 = fmaf(hv.y, wv, c1);
  }
  const float bv = bc1[col];
  const int r0 = n0 + hf * 2;
  gh [(r0 + 0) * 128 + col] = (half_t)c0;
  gh [(r0 + 1) * 128 + col] = (half_t)c1;
  gbh[(r0 + 0) * 128 + col] = (half_t)(c0 + bv);
  gbh[(r0 + 1) * 128 + col] = (half_t)(c1 + bv);
}

// ---------------------------------------------------------------------------
// edge kernel. 512 blocks x 512 threads = b(1b) x jhalf(1b) x ichunk(7b).
// Wave w (0..7) owns j-rows [jhalf*256 + w*32, +32).  LDS:
//   sW2/sW3 64KB weights (block-shared), sBf 1.5KB biases, sE 8KB/wave e2.
// ---------------------------------------------------------------------------
static __device__ inline f16x8 relu_sub8(f16x8 a, f16x8 b) {
  f16x8 d = a - b;
  const f16x8 z = {};
  return __builtin_elementwise_max(d, z);
}

__global__ __launch_bounds__(512, 2)
void edge_kernel(
    const half_t* __restrict__ gh, const half_t* __restrict__ gbh,
    const half_t* __restrict__ W2T, const half_t* __restrict__ W3T,
    const float* __restrict__ bc2, const float* __restrict__ bc3,
    const float* __restrict__ Wo, const float* __restrict__ bo,
    float* __restrict__ out)
{
  __shared__ __align__(16) half_t sW2[16384];    // 32 KB
  __shared__ __align__(16) half_t sW3[16384];    // 32 KB
  __shared__ __align__(16) float  sBf[384];      // bc2 | bc3 | Wo  (1.5 KB)
  __shared__ __align__(16) half_t sE[8 * 4096];  // 64 KB, 8 KB per wave

  const int t = threadIdx.x, lane = t & 63, w = t >> 6;
  const int c = lane & 15, q = lane >> 4;
  const int bid = blockIdx.x;
  const int b = bid >> 8, jh = (bid >> 7) & 1, ic = bid & 127;
  const int i0 = ic * 4;
  const int j0w = jh * 256 + w * 32;

  // ---- stage weights + biases into LDS (once per block) ----
  #pragma unroll
  for (int k = 0; k < 4; k++) {
    const int off = (k * 512 + t) * 8;
    *(f16x8*)(sW2 + off) = *(const f16x8*)(W2T + off);
    *(f16x8*)(sW3 + off) = *(const f16x8*)(W3T + off);
  }
  if (t < 384) sBf[t] = (t < 128) ? bc2[t] : ((t < 256) ? bc3[t - 128] : Wo[t - 256]);
  __syncthreads();

  const float bo0 = bo[0];
  // LDS pack address (halfs): ((q>>1)*16+c)*8 + (q&1)*4; +256 halfs when nt odd
  const int packoff = ((q >> 1) * 16 + c) * 8 + (q & 1) * 4;
  const int rdoff = lane * 8;

  // ---- gbh j-frags: independent of i, hoisted (32 VGPRs) ----
  f16x8 gj[4][2];
  #pragma unroll
  for (int ks = 0; ks < 4; ks++)
    #pragma unroll
    for (int jt = 0; jt < 2; jt++)
      gj[ks][jt] = *(const f16x8*)(gbh + (size_t)(b * 512 + j0w + jt * 16 + c) * 128 + ks * 32 + q * 8);

  // ---- gih for u=0 (prefetched for u+1 inside the loop) ----
  f16x8 gih[4];
  #pragma unroll
  for (int ks = 0; ks < 4; ks++)
    gih[ks] = *(const f16x8*)(gh + (size_t)(b * 512 + i0) * 128 + ks * 32 + q * 8);

  half_t* sEw = sE + w * 4096;

  #pragma unroll 1
  for (int u = 0; u < 4; u++) {
    const int i = i0 + u;

    // ---- phase A: e1[ks][jt] from gj (regs) and gih (prefetched) ----
    f16x8 e1[4][2];
    #pragma unroll
    for (int ks = 0; ks < 4; ks++)
      #pragma unroll
      for (int jt = 0; jt < 2; jt++)
        e1[ks][jt] = relu_sub8(gj[ks][jt], gih[ks]);

    // gih dead -> immediately issue loads for u+1 (hide L2 under B+C)
    {
      const int inx = i0 + ((u + 1) & 3);
      #pragma unroll
      for (int ks = 0; ks < 4; ks++)
        gih[ks] = *(const f16x8*)(gh + (size_t)(b * 512 + inx) * 128 + ks * 32 + q * 8);
    }

    // ---- phase B: layer 2, wf a/b software pipeline ----
    {
      f16x8 wfa[4], wfb[4];
      #pragma unroll
      for (int ks = 0; ks < 4; ks++)
        wfa[ks] = *(const f16x8*)(sW2 + ks * 512 + rdoff);       // nt = 0
      #pragma unroll 1
      for (int nt2 = 0; nt2 < 4; nt2++) {
        const int na = nt2 * 2, nb = na + 1;
        #pragma unroll
        for (int ks = 0; ks < 4; ks++)
          wfb[ks] = *(const f16x8*)(sW2 + nb * 2048 + ks * 512 + rdoff);
        // compute na with wfa
        {
          const f32x4 b2 = *(const f32x4*)(sBf + na * 16 + q * 4);
          f32x4 acc[2] = {b2, b2};
          __builtin_amdgcn_s_setprio(1);
          #pragma unroll
          for (int ks = 0; ks < 4; ks++)
            #pragma unroll
            for (int jt = 0; jt < 2; jt++)
              acc[jt] = __builtin_amdgcn_mfma_f32_16x16x32_f16(wfa[ks], e1[ks][jt], acc[jt], 0, 0, 0);
          __builtin_amdgcn_s_setprio(0);
          const int po = ((na >> 1) * 512) + packoff;            // na even
          #pragma unroll
          for (int jt = 0; jt < 2; jt++) {
            const f32x4 v = acc[jt];
            f16x2 h01, h23;
            h01[0] = (half_t)fmaxf(v[0], 0.f); h01[1] = (half_t)fmaxf(v[1], 0.f);
            h23[0] = (half_t)fmaxf(v[2], 0.f); h23[1] = (half_t)fmaxf(v[3], 0.f);
            uint2 uv;
            uv.x = __builtin_bit_cast(unsigned int, h01);
            uv.y = __builtin_bit_cast(unsigned int, h23);
            *(uint2*)(sEw + jt * 2048 + po) = uv;
          }
        }
        // prefetch next-a ((na+2)&7 wraps harmlessly on last iter)
        #pragma unroll
        for (int ks = 0; ks < 4; ks++)
          wfa[ks] = *(const f16x8*)(sW2 + ((na + 2) & 7) * 2048 + ks * 512 + rdoff);
        // compute nb with wfb
        {
          const f32x4 b2 = *(const f32x4*)(sBf + nb * 16 + q * 4);
          f32x4 acc[2] = {b2, b2};
          __builtin_amdgcn_s_setprio(1);
          #pragma unroll
          for (int ks = 0; ks < 4; ks++)
            #pragma unroll
            for (int jt = 0; jt < 2; jt++)
              acc[jt] = __builtin_amdgcn_mfma_f32_16x16x32_f16(wfb[ks], e1[ks][jt], acc[jt], 0, 0, 0);
          __builtin_amdgcn_s_setprio(0);
          const int po = ((nb >> 1) * 512) + packoff + 256;      // nb odd
          #pragma unroll
          for (int jt = 0; jt < 2; jt++) {
            const f32x4 v = acc[jt];
            f16x2 h01, h23;
            h01[0] = (half_t)fmaxf(v[0], 0.f); h01[1] = (half_t)fmaxf(v[1], 0.f);
            h23[0] = (half_t)fmaxf(v[2], 0.f); h23[1] = (half_t)fmaxf(v[3], 0.f);
            uint2 uv;
            uv.x = __builtin_bit_cast(unsigned int, h01);
            uv.y = __builtin_bit_cast(unsigned int, h23);
            *(uint2*)(sEw + jt * 2048 + po) = uv;
          }
        }
      }
    }

    // ---- phase C: layer 3; be from LDS, wf a/b software pipeline ----
    {
      f16x8 be[4][2];
      #pragma unroll
      for (int ks3 = 0; ks3 < 4; ks3++)
        #pragma unroll
        for (int jt = 0; jt < 2; jt++)
          be[ks3][jt] = *(const f16x8*)(sEw + (jt * 4 + ks3) * 512 + rdoff);

      f16x8 wfa[4], wfb[4];
      #pragma unroll
      for (int ks = 0; ks < 4; ks++)
        wfa[ks] = *(const f16x8*)(sW3 + ks * 512 + rdoff);       // mt = 0
      float p[2] = {0.f, 0.f};
      #pragma unroll 1
      for (int mt2 = 0; mt2 < 4; mt2++) {
        const int ma = mt2 * 2, mb = ma + 1;
        #pragma unroll
        for (int ks = 0; ks < 4; ks++)
          wfb[ks] = *(const f16x8*)(sW3 + mb * 2048 + ks * 512 + rdoff);
        // compute ma with wfa
        {
          const f32x4 b3 = *(const f32x4*)(sBf + 128 + ma * 16 + q * 4);
          f32x4 acc[2] = {b3, b3};
          __builtin_amdgcn_s_setprio(1);
          #pragma unroll
          for (int ks = 0; ks < 4; ks++)
            #pragma unroll
            for (int jt = 0; jt < 2; jt++)
              acc[jt] = __builtin_amdgcn_mfma_f32_16x16x32_f16(wfa[ks], be[ks][jt], acc[jt], 0, 0, 0);
          __builtin_amdgcn_s_setprio(0);
          const f32x4 wo = *(const f32x4*)(sBf + 256 + ma * 16 + q * 4);
          #pragma unroll
          for (int jt = 0; jt < 2; jt++)
            #pragma unroll
            for (int r = 0; r < 4; r++)
              p[jt] = fmaf(fmaxf(acc[jt][r], 0.f), wo[r], p[jt]);
        }
        // prefetch next-a
        #pragma unroll
        for (int ks = 0; ks < 4; ks++)
          wfa[ks] = *(const f16x8*)(sW3 + ((ma + 2) & 7) * 2048 + ks * 512 + rdoff);
        // compute mb with wfb
        {
          const f32x4 b3 = *(const f32x4*)(sBf + 128 + mb * 16 + q * 4);
          f32x4 acc[2] = {b3, b3};
          __builtin_amdgcn_s_setprio(1);
          #pragma unroll
          for (int ks = 0; ks < 4; ks++)
            #pragma unroll
            for (int jt = 0; jt < 2; jt++)
              acc[jt] = __builtin_amdgcn_mfma_f32_16x16x32_f16(wfb[ks], be[ks][jt], acc[jt], 0, 0, 0);
          __builtin_amdgcn_s_setprio(0);
          const f32x4 wo = *(const f32x4*)(sBf + 256 + mb * 16 + q * 4);
          #pragma unroll
          for (int jt = 0; jt < 2; jt++)
            #pragma unroll
            for (int r = 0; r < 4; r++)
              p[jt] = fmaf(fmaxf(acc[jt][r], 0.f), wo[r], p[jt]);
        }
      }

      // ---- epilogue: reduce over q (rows n3 split across q), store ----
      #pragma unroll
      for (int jt = 0; jt < 2; jt++) {
        p[jt] += __shfl_xor(p[jt], 16, 64);
        p[jt] += __shfl_xor(p[jt], 32, 64);
      }
      if (q == 0) {
        const size_t base = ((size_t)(b * 512 + i)) * 512 + j0w;
        #pragma unroll
        for (int jt = 0; jt < 2; jt++)
          out[base + jt * 16 + c] = p[jt] + bo0;
      }
    }
  }
}

// ---------------------------------------------------------------------------
extern "C" void kernel_launch(void* const* d_in, const int* in_sizes, int n_in,
                              void* d_out, int out_size, void* d_ws, size_t ws_size,
                              hipStream_t stream)
{
  const float* x   = (const float*)d_in[0];
  const float* Wa  = (const float*)d_in[1];
  const float* ba  = (const float*)d_in[2];
  const float* Wb  = (const float*)d_in[3];
  const float* bb  = (const float*)d_in[4];
  const float* Wc1 = (const float*)d_in[5];
  const float* bc1 = (const float*)d_in[6];
  const float* Wc2 = (const float*)d_in[7];
  const float* bc2 = (const float*)d_in[8];
  const float* Wc3 = (const float*)d_in[9];
  const float* bc3 = (const float*)d_in[10];
  const float* Wo  = (const float*)d_in[11];
  const float* bo  = (const float*)d_in[12];
  float* out = (float*)d_out;

  char* ws = (char*)d_ws;
  half_t* gh  = (half_t*)ws;                      // 256 KB
  half_t* gbh = (half_t*)(ws + 262144);           // 256 KB
  half_t* W2T = (half_t*)(ws + 524288);           // 32 KB
  half_t* W3T = (half_t*)(ws + 557056);           // 32 KB

  prep_kernel<<<272, 256, 0, stream>>>(x, Wa, ba, Wb, bb, Wc1, bc1, Wc2, Wc3,
                                       gh, gbh, W2T, W3T);
  edge_kernel<<<512, 512, 0, stream>>>(gh, gbh, W2T, W3T, bc2, bc3, Wo, bo, out);
}

// Round 8
// 122.598 us; speedup vs baseline: 2.7872x; 1.0238x over previous
//
#include <hip/hip_runtime.h>

// SimpleEdgeModel round 14: two weight streams on two pipes, jt=4, 160KB LDS.
// R13 post-mortem: compiler sank the explicit prefetches (VGPR stayed 92) ->
// only the costs remained, 49.1us vs R8 42.4.  Arc theory: weight-DS/j only
// drops with more j per wave; j-state needs regs AND e2-LDS (16KB per 64-j
// wave); with W2+W3 both in LDS (64KB) the cap forces jt=2 -> R8's 80k-cy DS
// floor.  Fix: W3 streams from L1 (32KB = exactly L1-size -> resident
// broadcast for all 8 waves), freeing LDS: 32(W2) + 8x16(e2) = 160KB exactly
// (AITER fmha_v3 precedent for 160KB static on gfx950).  Biases -> cached
// global loads.  jt=4 halves per-j weight traffic vs R8.  Monolithic waves,
// BARRIER-FREE (R8's proven property; R11/R12 lockstep loses).
// Budget per CU-u: DS 6.1k cy, L1 6.6k cy, MFMA 9.9k cy/SIMD -> MFMA-bound
// with margin.  Reg peak ~= R12's measured per-role 92 + eps (e1[4][4] or
// be[4][4] = 64, never both; wf/acc transient) -> no spills expected
// (FETCH_SIZE flat is the check; R10 showed the balloon signature).
//
// out[b,i,j] = Wo.relu(W3^T.relu(W2^T.relu(g_j+bc1-g_i)+bc2)+bc3)+bo
// g = nodeMLP(x)@Wc1.  Per wave: 64 j-rows x 4 i-units.

typedef _Float16 half_t;
typedef __attribute__((ext_vector_type(2))) _Float16 f16x2;
typedef __attribute__((ext_vector_type(8))) _Float16 f16x8;
typedef __attribute__((ext_vector_type(4))) float f32x4;

// ws layout:
//   gh  : 1024*128 f16 @ 0        = f16(g)
//   gbh : 1024*128 f16 @ 262144   = f16(g + bc1)
//   W2T : 16384 f16    @ 524288   (frag-packed Wc2, (nt*4+ks) order)
//   W3T : 16384 f16    @ 557056

// ---------------------------------------------------------------------------
// prep: blocks 0..255 node MLP (4 nodes/block); 256..271 weight frag pack.
// Frag (nt,ks), lane L=q*16+c, elem e  <-  Wsrc[32ks+8q+e][16nt+c].
// ---------------------------------------------------------------------------
__global__ __launch_bounds__(256) void prep_kernel(
    const float* __restrict__ x, const float* __restrict__ Wa, const float* __restrict__ ba,
    const float* __restrict__ Wb, const float* __restrict__ bb, const float* __restrict__ Wc1,
    const float* __restrict__ bc1, const float* __restrict__ Wc2, const float* __restrict__ Wc3,
    half_t* __restrict__ gh, half_t* __restrict__ gbh,
    half_t* __restrict__ W2T, half_t* __restrict__ W3T)
{
  const int t = threadIdx.x;
  if (blockIdx.x >= 256) {
    const int bid = blockIdx.x - 256;            // layer(1b) x ntile(3b)
    const int layer = bid >> 3, nt = bid & 7;
    const int ks = t >> 6, L = t & 63, q = L >> 4, cc = L & 15;
    const float* src = layer ? Wc3 : Wc2;
    half_t* dst = layer ? W3T : W2T;
    f16x8 v;
    #pragma unroll
    for (int e = 0; e < 8; e++)
      v[e] = (half_t)src[(32 * ks + 8 * q + e) * 128 + 16 * nt + cc];
    *(f16x8*)(dst + (nt * 4 + ks) * 512 + L * 8) = v;   // ks-frags contiguous per nt
    return;
  }
  __shared__ float sx[64 * 6];
  __shared__ float sh1[128 * 6];
  __shared__ float sh2[128 * 6];
  const int n0 = blockIdx.x * 4;
  const int col = t & 127, hf = t >> 7;

  sx[(t & 63) * 6 + (t >> 6)] = x[(n0 + (t >> 6)) * 64 + (t & 63)];
  __syncthreads();

  float a0 = ba[col], a1 = a0;
  #pragma unroll
  for (int cc = 0; cc < 64; cc++) {
    const float wv = Wa[cc * 128 + col];
    const float2 xv = *(const float2*)(sx + cc * 6 + hf * 2);
    a0 = fmaf(xv.x, wv, a0); a1 = fmaf(xv.y, wv, a1);
  }
  *(float2*)(sh1 + col * 6 + hf * 2) = make_float2(fmaxf(a0, 0.f), fmaxf(a1, 0.f));
  __syncthreads();

  float b0 = bb[col], b1 = b0;
  #pragma unroll
  for (int k = 0; k < 128; k++) {
    const float wv = Wb[k * 128 + col];
    const float2 hv = *(const float2*)(sh1 + k * 6 + hf * 2);
    b0 = fmaf(hv.x, wv, b0); b1 = fmaf(hv.y, wv, b1);
  }
  *(float2*)(sh2 + col * 6 + hf * 2) = make_float2(fmaxf(b0, 0.f), fmaxf(b1, 0.f));
  __syncthreads();

  float c0 = 0.f, c1 = 0.f;
  #pragma unroll
  for (int k = 0; k < 128; k++) {
    const float wv = Wc1[k * 128 + col];
    const float2 hv = *(const float2*)(sh2 + k * 6 + hf * 2);
    c0 = fmaf(hv.x, wv, c0); c1 = fmaf(hv.y, wv, c1);
  }
  const float bv = bc1[col];
  const int r0 = n0 + hf * 2;
  gh [(r0 + 0) * 128 + col] = (half_t)c0;
  gh [(r0 + 1) * 128 + col] = (half_t)c1;
  gbh[(r0 + 0) * 128 + col] = (half_t)(c0 + bv);
  gbh[(r0 + 1) * 128 + col] = (half_t)(c1 + bv);
}

// ---------------------------------------------------------------------------
// edge kernel. 256 blocks x 512 threads = b(1b) x ichunk(7b, 4 i each).
// Wave w owns j-rows [w*64, +64) (block covers all 512 j); 4 i-units.
// LDS: sW2 32KB (block-shared) + sE 16KB/wave e2 handoff = 160KB exactly.
// W3 + biases stream from L1 (W3T is 32KB = L1-resident after first pass).
// No barriers in the u-loop: per-wave-private e2 slot, self-scheduling.
// ---------------------------------------------------------------------------
static __device__ inline f16x8 relu_sub8(f16x8 a, f16x8 b) {
  f16x8 d = a - b;
  const f16x8 z = {};
  return __builtin_elementwise_max(d, z);
}

__global__ __launch_bounds__(512)
void edge_kernel(
    const half_t* __restrict__ gh, const half_t* __restrict__ gbh,
    const half_t* __restrict__ W2T, const half_t* __restrict__ W3T,
    const float* __restrict__ bc2, const float* __restrict__ bc3,
    const float* __restrict__ Wo, const float* __restrict__ bo,
    float* __restrict__ out)
{
  __shared__ __align__(16) half_t sW2[16384];    // 32 KB
  __shared__ __align__(16) half_t sE[8 * 8192];  // 128 KB, 16 KB per wave

  const int t = threadIdx.x, lane = t & 63, w = t >> 6;
  const int c = lane & 15, q = lane >> 4;
  const int bid = blockIdx.x;
  const int b = bid >> 7, ic = bid & 127;
  const int i0 = ic * 4;
  const int j0 = w * 64;

  // ---- stage W2 into LDS (once per block) ----
  #pragma unroll
  for (int k = 0; k < 4; k++) {
    const int off = (k * 512 + t) * 8;
    *(f16x8*)(sW2 + off) = *(const f16x8*)(W2T + off);
  }
  __syncthreads();

  const float bo0 = bo[0];
  // LDS pack address (halfs): ((q>>1)*16+c)*8 + (q&1)*4; +256 halfs when nt odd
  const int packoff = ((q >> 1) * 16 + c) * 8 + (q & 1) * 4;
  const int rdoff = lane * 8;
  half_t* sEw = sE + w * 8192;

  #pragma unroll 1
  for (int u = 0; u < 4; u++) {
    const int i = i0 + u;

    // ---- phase A: e1[ks][jt] (64 VGPRs; gj/gih transient) ----
    f16x8 e1[4][4];
    {
      f16x8 gih[4];
      #pragma unroll
      for (int ks = 0; ks < 4; ks++)
        gih[ks] = *(const f16x8*)(gh + (size_t)(b * 512 + i) * 128 + ks * 32 + q * 8);
      #pragma unroll
      for (int ks = 0; ks < 4; ks++)
        #pragma unroll
        for (int jt = 0; jt < 4; jt++) {
          const f16x8 gj = *(const f16x8*)(gbh + (size_t)(b * 512 + j0 + jt * 16 + c) * 128 + ks * 32 + q * 8);
          e1[ks][jt] = relu_sub8(gj, gih[ks]);
        }
    }

    // ---- phase B: layer 2; W2 from LDS, bias from global, e2 -> own slot --
    #pragma unroll 1
    for (int nt = 0; nt < 8; nt++) {
      f16x8 wf[4];
      #pragma unroll
      for (int ks = 0; ks < 4; ks++)
        wf[ks] = *(const f16x8*)(sW2 + (nt * 4 + ks) * 512 + rdoff);
      const f32x4 b2 = *(const f32x4*)(bc2 + nt * 16 + q * 4);
      f32x4 acc[4] = {b2, b2, b2, b2};
      __builtin_amdgcn_s_setprio(1);
      #pragma unroll
      for (int ks = 0; ks < 4; ks++)
        #pragma unroll
        for (int jt = 0; jt < 4; jt++)
          acc[jt] = __builtin_amdgcn_mfma_f32_16x16x32_f16(wf[ks], e1[ks][jt], acc[jt], 0, 0, 0);
      __builtin_amdgcn_s_setprio(0);
      const int po = ((nt >> 1) * 512) + packoff + (nt & 1) * 256;   // ks3 slot base
      #pragma unroll
      for (int jt = 0; jt < 4; jt++) {
        const f32x4 v = acc[jt];
        f16x2 h01, h23;
        h01[0] = (half_t)fmaxf(v[0], 0.f); h01[1] = (half_t)fmaxf(v[1], 0.f);
        h23[0] = (half_t)fmaxf(v[2], 0.f); h23[1] = (half_t)fmaxf(v[3], 0.f);
        uint2 uv;
        uv.x = __builtin_bit_cast(unsigned int, h01);
        uv.y = __builtin_bit_cast(unsigned int, h23);
        *(uint2*)(sEw + jt * 2048 + po) = uv;    // (jt*4+ks3)*512 = jt*2048+ks3*512
      }
    }

    // ---- phase C: layer 3; be from own slot, W3/biases from L1 ----
    {
      f16x8 be[4][4];
      #pragma unroll
      for (int ks3 = 0; ks3 < 4; ks3++)
        #pragma unroll
        for (int jt = 0; jt < 4; jt++)
          be[ks3][jt] = *(const f16x8*)(sEw + (jt * 4 + ks3) * 512 + rdoff);

      float p[4] = {0.f, 0.f, 0.f, 0.f};
      #pragma unroll 1
      for (int mt = 0; mt < 8; mt++) {
        f16x8 wf[4];
        #pragma unroll
        for (int ks3 = 0; ks3 < 4; ks3++)
          wf[ks3] = *(const f16x8*)(W3T + (mt * 4 + ks3) * 512 + rdoff);
        const f32x4 b3 = *(const f32x4*)(bc3 + mt * 16 + q * 4);
        f32x4 acc[4] = {b3, b3, b3, b3};
        __builtin_amdgcn_s_setprio(1);
        #pragma unroll
        for (int ks3 = 0; ks3 < 4; ks3++)
          #pragma unroll
          for (int jt = 0; jt < 4; jt++)
            acc[jt] = __builtin_amdgcn_mfma_f32_16x16x32_f16(wf[ks3], be[ks3][jt], acc[jt], 0, 0, 0);
        __builtin_amdgcn_s_setprio(0);
        const f32x4 wo = *(const f32x4*)(Wo + mt * 16 + q * 4);
        #pragma unroll
        for (int jt = 0; jt < 4; jt++)
          #pragma unroll
          for (int rr = 0; rr < 4; rr++)
            p[jt] = fmaf(fmaxf(acc[jt][rr], 0.f), wo[rr], p[jt]);
      }

      // ---- epilogue: reduce over q (rows n3 split across q), store ----
      #pragma unroll
      for (int jt = 0; jt < 4; jt++) {
        p[jt] += __shfl_xor(p[jt], 16, 64);
        p[jt] += __shfl_xor(p[jt], 32, 64);
      }
      if (q == 0) {
        const size_t base = ((size_t)(b * 512 + i)) * 512 + j0;
        #pragma unroll
        for (int jt = 0; jt < 4; jt++)
          out[base + jt * 16 + c] = p[jt] + bo0;
      }
    }
  }
}

// ---------------------------------------------------------------------------
extern "C" void kernel_launch(void* const* d_in, const int* in_sizes, int n_in,
                              void* d_out, int out_size, void* d_ws, size_t ws_size,
                              hipStream_t stream)
{
  const float* x   = (const float*)d_in[0];
  const float* Wa  = (const float*)d_in[1];
  const float* ba  = (const float*)d_in[2];
  const float* Wb  = (const float*)d_in[3];
  const float* bb  = (const float*)d_in[4];
  const float* Wc1 = (const float*)d_in[5];
  const float* bc1 = (const float*)d_in[6];
  const float* Wc2 = (const float*)d_in[7];
  const float* bc2 = (const float*)d_in[8];
  const float* Wc3 = (const float*)d_in[9];
  const float* bc3 = (const float*)d_in[10];
  const float* Wo  = (const float*)d_in[11];
  const float* bo  = (const float*)d_in[12];
  float* out = (float*)d_out;

  char* ws = (char*)d_ws;
  half_t* gh  = (half_t*)ws;                      // 256 KB
  half_t* gbh = (half_t*)(ws + 262144);           // 256 KB
  half_t* W2T = (half_t*)(ws + 524288);           // 32 KB
  half_t* W3T = (half_t*)(ws + 557056);           // 32 KB

  prep_kernel<<<272, 256, 0, stream>>>(x, Wa, ba, Wb, bb, Wc1, bc1, Wc2, Wc3,
                                       gh, gbh, W2T, W3T);
  edge_kernel<<<256, 512, 0, stream>>>(gh, gbh, W2T, W3T, bc2, bc3, Wo, bo, out);
}

// Round 9
// 121.822 us; speedup vs baseline: 2.8049x; 1.0064x over previous
//
#include <hip/hip_runtime.h>

// SimpleEdgeModel round 15: R14 + anti-phase wave desync + dependent-load fixes.
// R14 post-mortem: byte budget landed exactly (DS 10.2us, L1 14.4us, MFMA
// 16.6us, no spills) but time = SERIAL SUM (45.8us, MfmaUtil 28%): the 2
// waves/SIMD start barrier-aligned, run identical phase sequences -> convoy:
// both in A (L2), both in B (DS+MFMA), both in C (L1+MFMA); same-pipe
// contention + zero cross-pipe overlap.  R6-R14 all 42-50us for this reason.
// Fixes (structure unchanged):
//   1) waves 4-7 s_sleep(64) (~4k cy ~ half u-period) after staging sync ->
//      anti-phase with their SIMD partner (w%4 mapping pairs w and w+4).
//      Anti-phase is self-preserving: offset waves see less contention.
//   2) acc zero-init; bias applied at pack (B) / fold (C) -> bias loads
//      issue at iter top, consumed ~400cy later (hidden), not at acc-init.
//   3) C phase: wf a/b rotation over mt-pairs -> W3 L1 latency (~150-200cy
//      x8/u) hides under the previous mt's MFMA cluster.  C live regs ~116.
// Check: FETCH_SIZE must stay ~1454KB (balloon = spills, R10 signature).
//
// out[b,i,j] = Wo.relu(W3^T.relu(W2^T.relu(g_j+bc1-g_i)+bc2)+bc3)+bo
// g = nodeMLP(x)@Wc1.  Per wave: 64 j-rows x 4 i-units, barrier-free loop.

typedef _Float16 half_t;
typedef __attribute__((ext_vector_type(2))) _Float16 f16x2;
typedef __attribute__((ext_vector_type(8))) _Float16 f16x8;
typedef __attribute__((ext_vector_type(4))) float f32x4;

// ws layout:
//   gh  : 1024*128 f16 @ 0        = f16(g)
//   gbh : 1024*128 f16 @ 262144   = f16(g + bc1)
//   W2T : 16384 f16    @ 524288   (frag-packed Wc2, (nt*4+ks) order)
//   W3T : 16384 f16    @ 557056

// ---------------------------------------------------------------------------
// prep: blocks 0..255 node MLP (4 nodes/block); 256..271 weight frag pack.
// Frag (nt,ks), lane L=q*16+c, elem e  <-  Wsrc[32ks+8q+e][16nt+c].
// ---------------------------------------------------------------------------
__global__ __launch_bounds__(256) void prep_kernel(
    const float* __restrict__ x, const float* __restrict__ Wa, const float* __restrict__ ba,
    const float* __restrict__ Wb, const float* __restrict__ bb, const float* __restrict__ Wc1,
    const float* __restrict__ bc1, const float* __restrict__ Wc2, const float* __restrict__ Wc3,
    half_t* __restrict__ gh, half_t* __restrict__ gbh,
    half_t* __restrict__ W2T, half_t* __restrict__ W3T)
{
  const int t = threadIdx.x;
  if (blockIdx.x >= 256) {
    const int bid = blockIdx.x - 256;            // layer(1b) x ntile(3b)
    const int layer = bid >> 3, nt = bid & 7;
    const int ks = t >> 6, L = t & 63, q = L >> 4, cc = L & 15;
    const float* src = layer ? Wc3 : Wc2;
    half_t* dst = layer ? W3T : W2T;
    f16x8 v;
    #pragma unroll
    for (int e = 0; e < 8; e++)
      v[e] = (half_t)src[(32 * ks + 8 * q + e) * 128 + 16 * nt + cc];
    *(f16x8*)(dst + (nt * 4 + ks) * 512 + L * 8) = v;   // ks-frags contiguous per nt
    return;
  }
  __shared__ float sx[64 * 6];
  __shared__ float sh1[128 * 6];
  __shared__ float sh2[128 * 6];
  const int n0 = blockIdx.x * 4;
  const int col = t & 127, hf = t >> 7;

  sx[(t & 63) * 6 + (t >> 6)] = x[(n0 + (t >> 6)) * 64 + (t & 63)];
  __syncthreads();

  float a0 = ba[col], a1 = a0;
  #pragma unroll
  for (int cc = 0; cc < 64; cc++) {
    const float wv = Wa[cc * 128 + col];
    const float2 xv = *(const float2*)(sx + cc * 6 + hf * 2);
    a0 = fmaf(xv.x, wv, a0); a1 = fmaf(xv.y, wv, a1);
  }
  *(float2*)(sh1 + col * 6 + hf * 2) = make_float2(fmaxf(a0, 0.f), fmaxf(a1, 0.f));
  __syncthreads();

  float b0 = bb[col], b1 = b0;
  #pragma unroll
  for (int k = 0; k < 128; k++) {
    const float wv = Wb[k * 128 + col];
    const float2 hv = *(const float2*)(sh1 + k * 6 + hf * 2);
    b0 = fmaf(hv.x, wv, b0); b1 = fmaf(hv.y, wv, b1);
  }
  *(float2*)(sh2 + col * 6 + hf * 2) = make_float2(fmaxf(b0, 0.f), fmaxf(b1, 0.f));
  __syncthreads();

  float c0 = 0.f, c1 = 0.f;
  #pragma unroll
  for (int k = 0; k < 128; k++) {
    const float wv = Wc1[k * 128 + col];
    const float2 hv = *(const float2*)(sh2 + k * 6 + hf * 2);
    c0 = fmaf(hv.x, wv, c0); c1 = fmaf(hv.y, wv, c1);
  }
  const float bv = bc1[col];
  const int r0 = n0 + hf * 2;
  gh [(r0 + 0) * 128 + col] = (half_t)c0;
  gh [(r0 + 1) * 128 + col] = (half_t)c1;
  gbh[(r0 + 0) * 128 + col] = (half_t)(c0 + bv);
  gbh[(r0 + 1) * 128 + col] = (half_t)(c1 + bv);
}

// ---------------------------------------------------------------------------
// edge kernel. 256 blocks x 512 threads = b(1b) x ichunk(7b, 4 i each).
// Wave w owns j-rows [w*64, +64); 4 i-units.  LDS: sW2 32KB + sE 16KB/wave
// = 160KB.  W3 + biases from L1.  No barriers in the u-loop.
// Waves 4-7 sleep ~4k cy after staging -> anti-phase with SIMD partner.
// ---------------------------------------------------------------------------
static __device__ inline f16x8 relu_sub8(f16x8 a, f16x8 b) {
  f16x8 d = a - b;
  const f16x8 z = {};
  return __builtin_elementwise_max(d, z);
}

__global__ __launch_bounds__(512)
void edge_kernel(
    const half_t* __restrict__ gh, const half_t* __restrict__ gbh,
    const half_t* __restrict__ W2T, const half_t* __restrict__ W3T,
    const float* __restrict__ bc2, const float* __restrict__ bc3,
    const float* __restrict__ Wo, const float* __restrict__ bo,
    float* __restrict__ out)
{
  __shared__ __align__(16) half_t sW2[16384];    // 32 KB
  __shared__ __align__(16) half_t sE[8 * 8192];  // 128 KB, 16 KB per wave

  const int t = threadIdx.x, lane = t & 63, w = t >> 6;
  const int c = lane & 15, q = lane >> 4;
  const int bid = blockIdx.x;
  const int b = bid >> 7, ic = bid & 127;
  const int i0 = ic * 4;
  const int j0 = w * 64;

  // ---- stage W2 into LDS (once per block) ----
  #pragma unroll
  for (int k = 0; k < 4; k++) {
    const int off = (k * 512 + t) * 8;
    *(f16x8*)(sW2 + off) = *(const f16x8*)(W2T + off);
  }
  __syncthreads();

  // ---- anti-phase desync: waves 4-7 (SIMD partners of 0-3) sleep ~4k cy --
  if (w >= 4) __builtin_amdgcn_s_sleep(64);

  const float bo0 = bo[0];
  // LDS pack address (halfs): ((q>>1)*16+c)*8 + (q&1)*4; +256 halfs when nt odd
  const int packoff = ((q >> 1) * 16 + c) * 8 + (q & 1) * 4;
  const int rdoff = lane * 8;
  half_t* sEw = sE + w * 8192;

  #pragma unroll 1
  for (int u = 0; u < 4; u++) {
    const int i = i0 + u;

    // ---- phase A: e1[ks][jt] (64 VGPRs; gj/gih transient) ----
    f16x8 e1[4][4];
    {
      f16x8 gih[4];
      #pragma unroll
      for (int ks = 0; ks < 4; ks++)
        gih[ks] = *(const f16x8*)(gh + (size_t)(b * 512 + i) * 128 + ks * 32 + q * 8);
      #pragma unroll
      for (int ks = 0; ks < 4; ks++)
        #pragma unroll
        for (int jt = 0; jt < 4; jt++) {
          const f16x8 gj = *(const f16x8*)(gbh + (size_t)(b * 512 + j0 + jt * 16 + c) * 128 + ks * 32 + q * 8);
          e1[ks][jt] = relu_sub8(gj, gih[ks]);
        }
    }

    // ---- phase B: layer 2; W2 from LDS; acc zero-init, bias at pack ----
    #pragma unroll 1
    for (int nt = 0; nt < 8; nt++) {
      const f32x4 b2 = *(const f32x4*)(bc2 + nt * 16 + q * 4);   // consumed at pack
      f16x8 wf[4];
      #pragma unroll
      for (int ks = 0; ks < 4; ks++)
        wf[ks] = *(const f16x8*)(sW2 + (nt * 4 + ks) * 512 + rdoff);
      f32x4 acc[4] = {};
      __builtin_amdgcn_s_setprio(1);
      #pragma unroll
      for (int ks = 0; ks < 4; ks++)
        #pragma unroll
        for (int jt = 0; jt < 4; jt++)
          acc[jt] = __builtin_amdgcn_mfma_f32_16x16x32_f16(wf[ks], e1[ks][jt], acc[jt], 0, 0, 0);
      __builtin_amdgcn_s_setprio(0);
      const int po = ((nt >> 1) * 512) + packoff + (nt & 1) * 256;   // ks3 slot base
      #pragma unroll
      for (int jt = 0; jt < 4; jt++) {
        const f32x4 v = acc[jt];
        f16x2 h01, h23;
        h01[0] = (half_t)fmaxf(v[0] + b2[0], 0.f); h01[1] = (half_t)fmaxf(v[1] + b2[1], 0.f);
        h23[0] = (half_t)fmaxf(v[2] + b2[2], 0.f); h23[1] = (half_t)fmaxf(v[3] + b2[3], 0.f);
        uint2 uv;
        uv.x = __builtin_bit_cast(unsigned int, h01);
        uv.y = __builtin_bit_cast(unsigned int, h23);
        *(uint2*)(sEw + jt * 2048 + po) = uv;    // (jt*4+ks3)*512 = jt*2048+ks3*512
      }
    }

    // ---- phase C: layer 3; be from own slot; W3 a/b rotation over mt ----
    {
      f16x8 be[4][4];
      #pragma unroll
      for (int ks3 = 0; ks3 < 4; ks3++)
        #pragma unroll
        for (int jt = 0; jt < 4; jt++)
          be[ks3][jt] = *(const f16x8*)(sEw + (jt * 4 + ks3) * 512 + rdoff);

      f16x8 wfa[4], wfb[4];
      #pragma unroll
      for (int ks3 = 0; ks3 < 4; ks3++)
        wfa[ks3] = *(const f16x8*)(W3T + ks3 * 512 + rdoff);     // mt = 0

      float p[4] = {0.f, 0.f, 0.f, 0.f};
      #pragma unroll 1
      for (int mp = 0; mp < 4; mp++) {
        const int ma = mp * 2, mb = ma + 1;
        // prefetch mb while computing ma
        #pragma unroll
        for (int ks3 = 0; ks3 < 4; ks3++)
          wfb[ks3] = *(const f16x8*)(W3T + (mb * 4 + ks3) * 512 + rdoff);
        {
          const f32x4 b3 = *(const f32x4*)(bc3 + ma * 16 + q * 4);
          const f32x4 wo = *(const f32x4*)(Wo  + ma * 16 + q * 4);
          f32x4 acc[4] = {};
          __builtin_amdgcn_s_setprio(1);
          #pragma unroll
          for (int ks3 = 0; ks3 < 4; ks3++)
            #pragma unroll
            for (int jt = 0; jt < 4; jt++)
              acc[jt] = __builtin_amdgcn_mfma_f32_16x16x32_f16(wfa[ks3], be[ks3][jt], acc[jt], 0, 0, 0);
          __builtin_amdgcn_s_setprio(0);
          #pragma unroll
          for (int jt = 0; jt < 4; jt++)
            #pragma unroll
            for (int rr = 0; rr < 4; rr++)
              p[jt] = fmaf(fmaxf(acc[jt][rr] + b3[rr], 0.f), wo[rr], p[jt]);
        }
        // prefetch next-a while computing mb ((ma+2)&7 wraps harmlessly)
        #pragma unroll
        for (int ks3 = 0; ks3 < 4; ks3++)
          wfa[ks3] = *(const f16x8*)(W3T + (((ma + 2) & 7) * 4 + ks3) * 512 + rdoff);
        {
          const f32x4 b3 = *(const f32x4*)(bc3 + mb * 16 + q * 4);
          const f32x4 wo = *(const f32x4*)(Wo  + mb * 16 + q * 4);
          f32x4 acc[4] = {};
          __builtin_amdgcn_s_setprio(1);
          #pragma unroll
          for (int ks3 = 0; ks3 < 4; ks3++)
            #pragma unroll
            for (int jt = 0; jt < 4; jt++)
              acc[jt] = __builtin_amdgcn_mfma_f32_16x16x32_f16(wfb[ks3], be[ks3][jt], acc[jt], 0, 0, 0);
          __builtin_amdgcn_s_setprio(0);
          #pragma unroll
          for (int jt = 0; jt < 4; jt++)
            #pragma unroll
            for (int rr = 0; rr < 4; rr++)
              p[jt] = fmaf(fmaxf(acc[jt][rr] + b3[rr], 0.f), wo[rr], p[jt]);
        }
      }

      // ---- epilogue: reduce over q (rows n3 split across q), store ----
      #pragma unroll
      for (int jt = 0; jt < 4; jt++) {
        p[jt] += __shfl_xor(p[jt], 16, 64);
        p[jt] += __shfl_xor(p[jt], 32, 64);
      }
      if (q == 0) {
        const size_t base = ((size_t)(b * 512 + i)) * 512 + j0;
        #pragma unroll
        for (int jt = 0; jt < 4; jt++)
          out[base + jt * 16 + c] = p[jt] + bo0;
      }
    }
  }
}

// ---------------------------------------------------------------------------
extern "C" void kernel_launch(void* const* d_in, const int* in_sizes, int n_in,
                              void* d_out, int out_size, void* d_ws, size_t ws_size,
                              hipStream_t stream)
{
  const float* x   = (const float*)d_in[0];
  const float* Wa  = (const float*)d_in[1];
  const float* ba  = (const float*)d_in[2];
  const float* Wb  = (const float*)d_in[3];
  const float* bb  = (const float*)d_in[4];
  const float* Wc1 = (const float*)d_in[5];
  const float* bc1 = (const float*)d_in[6];
  const float* Wc2 = (const float*)d_in[7];
  const float* bc2 = (const float*)d_in[8];
  const float* Wc3 = (const float*)d_in[9];
  const float* bc3 = (const float*)d_in[10];
  const float* Wo  = (const float*)d_in[11];
  const float* bo  = (const float*)d_in[12];
  float* out = (float*)d_out;

  char* ws = (char*)d_ws;
  half_t* gh  = (half_t*)ws;                      // 256 KB
  half_t* gbh = (half_t*)(ws + 262144);           // 256 KB
  half_t* W2T = (half_t*)(ws + 524288);           // 32 KB
  half_t* W3T = (half_t*)(ws + 557056);           // 32 KB

  prep_kernel<<<272, 256, 0, stream>>>(x, Wa, ba, Wb, bb, Wc1, bc1, Wc2, Wc3,
                                       gh, gbh, W2T, W3T);
  edge_kernel<<<256, 512, 0, stream>>>(gh, gbh, W2T, W3T, bc2, bc3, Wo, bo, out);
}